// Round 12
// baseline (155.045 us; speedup 1.0000x reference)
//
#include <hip/hip_runtime.h>
#include <stdint.h>

// Problem constants
#define S_LEN   2048
#define BATCH   2
#define DM      1024
#define NHEADS  16
#define HD      64
#define WIN     256
#define MROWS   (BATCH * S_LEN)          // 4096
#define NX      (MROWS * DM)             // 4194304 x elements
#define NW      (DM * DM)                // 1048576 per weight

typedef unsigned short u16;
typedef unsigned int   u32;

using short8  = __attribute__((ext_vector_type(8))) short;   // 8 bf16 (4 VGPRs)
using floatx4 = __attribute__((ext_vector_type(4))) float;   // MFMA acc

__device__ __forceinline__ float bf2f(u16 u) {
    union { u32 u; float f; } v; v.u = ((u32)u) << 16; return v.f;
}
__device__ __forceinline__ u16 f2bf(float f) {
    union { float f; u32 u; } v; v.f = f;
    u32 u = v.u;
    u += 0x7fffu + ((u >> 16) & 1u);   // RNE
    return (u16)(u >> 16);
}

// async global->LDS, 16B per lane. LDS dest = wave-uniform base + lane*16.
__device__ __forceinline__ void load_lds16(const void* g, void* l) {
    __builtin_amdgcn_global_load_lds(
        (__attribute__((address_space(1))) void*)(uintptr_t)g,
        (__attribute__((address_space(3))) void*)(unsigned int)(uintptr_t)l,
        16, 0, 0);
}

// ---------------------------------------------------------------------------
// normalize + inline dtype probe. flag=0 -> bf16 inputs ; 1 -> fp32 inputs.
// R7 (kept, -6.4us): conversion loop vectorized x4 (G13). float4 load +
// ushort4 store; NX/NW multiples of 4 so no region straddle; dst 8B-aligned.
// ---------------------------------------------------------------------------
__global__ __launch_bounds__(256) void normalize_inputs(
        const void* x, const void* wq, const void* wk, const void* wv, const void* wo,
        u16* xb, u16* wcat, u16* wob, int* flag) {
    __shared__ int sbad;
    if (threadIdx.x == 0) sbad = 0;
    __syncthreads();
    int bad = 0;
    for (int i = threadIdx.x; i < 4096; i += 256) {
        float v = bf2f(((const u16*)x)[i]);
        if (!(fabsf(v) < 1e6f)) bad = 1;
    }
    if (bad) atomicOr(&sbad, 1);
    __syncthreads();
    const int mode = sbad;
    if (blockIdx.x == 0 && threadIdx.x == 0) flag[0] = mode;
    if (mode == 0) return;
    const int total4 = (NX + 4 * NW) >> 2;
    for (int i4 = blockIdx.x * blockDim.x + threadIdx.x; i4 < total4;
         i4 += gridDim.x * blockDim.x) {
        const int i = i4 << 2;
        const float* src; u16* dst; int li;
        if (i < NX)              { src = (const float*)x;  dst = xb;          li = i; }
        else if (i < NX + NW)    { src = (const float*)wq; dst = wcat;        li = i - NX; }
        else if (i < NX + 2*NW)  { src = (const float*)wk; dst = wcat + NW;   li = i - NX - NW; }
        else if (i < NX + 3*NW)  { src = (const float*)wv; dst = wcat + 2*NW; li = i - NX - 2*NW; }
        else                     { src = (const float*)wo; dst = wob;         li = i - NX - 3*NW; }
        float4 v = *(const float4*)(src + li);
        ushort4 o;
        o.x = f2bf(v.x); o.y = f2bf(v.y); o.z = f2bf(v.z); o.w = f2bf(v.w);
        *(ushort4*)(dst + li) = o;
    }
}

// ---------------------------------------------------------------------------
// Pipelined GEMM  C[M,N] = A[M,K] * B[N,K]^T  (bf16 in, fp32 acc)
// TBMxTBN tile, BK=32, 256 threads (4 waves). Double-buffered LDS, one
// __syncthreads per iter (implicit vmcnt(0) waits the current buffer).
// R1-R4: 256^2 8-wave QKV w/ counted waits+swizzle = schedule-invariant
// 43.5us AND ~10us downstream loss -> this 128^2 structure is system-best.
// R9 (REVERTED): XCD-chunked swizzle HURT (+5.3us, FETCH 28.75->35.9 MB) --
// x-fastest dispatch already shares B-panels among resident blocks (m160:
// swizzle costs when L3-fit and not HBM-bound). Do not re-apply.
// final_out==0: cols<1024 (Q) pre-scaled by QSCALE (0.125 * log2(e): attn
// uses exp2f, folding exp's hidden x1.4427 into this epilogue); cols>=2048
// (V) written TRANSPOSED into VT[bh][d][s] (R12: fusion beats a separate
// transpose kernel).
// ---------------------------------------------------------------------------
#define BK 32
#define QSCALE 0.180336880f   // 0.125 * log2(e) = (1/sqrt(64)) * 1.44269504

template<int TBM, int TBN>
__global__ __launch_bounds__(256) void gemm_lds(
        const u16* __restrict__ Araw, const u16* __restrict__ Anorm,
        const u16* __restrict__ B0, const u16* __restrict__ B1,
        const u16* __restrict__ B2, const u16* __restrict__ Bnorm,
        void* __restrict__ C, u16* __restrict__ VT,
        int M, int N, int K,
        const int* __restrict__ flag, int final_out) {
    constexpr int NI = TBM / 32, NF = TBN / 32;  // frags per wave (rows, cols)
    __shared__ __align__(16) u16 sA[2][TBM * BK];
    __shared__ __align__(16) u16 sB[2][TBN * BK];

    const int mode = flag[0];
    const int tid  = threadIdx.x;
    const int lane = tid & 63, wave = tid >> 6;
    const int m0  = blockIdx.x * TBM;
    const int n0g = blockIdx.y * TBN;
    const int third = n0g >> 10;                 // which weight (1024-col thirds)
    const u16* A = mode ? Anorm : Araw;
    const u16* B = mode ? (Bnorm + (size_t)third * NW)
                        : (third == 0 ? B0 : (third == 1 ? B1 : B2));
    const int n0 = n0g - third * 1024;           // row within selected weight

    const int srow = lane >> 2;                  // row within 16-row group
    const int scol = (lane & 3) * 8;             // element col within BK
    const u16* gA = A + (size_t)(m0 + wave * 16 + srow) * K + scol;
    const u16* gB = B + (size_t)(n0 + wave * 16 + srow) * K + scol;
    const size_t rstep = (size_t)64 * K;
    const int lofs = wave * 16 * BK;             // wave-uniform LDS base offset

    const int n16 = lane & 15, quad = lane >> 4;
    const int m_off = (wave >> 1) * (TBM / 2), n_off = (wave & 1) * (TBN / 2);

    floatx4 acc[NI][NF] = {};
    const int NIT = K / BK;

    auto issue = [&](int k0, int buf) {
        #pragma unroll
        for (int ia = 0; ia < TBM / 64; ++ia)
            load_lds16(gA + k0 + ia * rstep, sA[buf] + lofs + ia * 64 * BK);
        #pragma unroll
        for (int ib = 0; ib < TBN / 64; ++ib)
            load_lds16(gB + k0 + ib * rstep, sB[buf] + lofs + ib * 64 * BK);
    };

    issue(0, 0);
    for (int it = 0; it < NIT; ++it) {
        const int cur = it & 1;
        __syncthreads();   // vmcnt(0): buf[cur] staged; also fences prev compute
        if (it + 1 < NIT) issue((it + 1) * BK, 1 - cur);
        short8 af[NI], bfr[NF];
        #pragma unroll
        for (int i = 0; i < NI; ++i)
            af[i] = *(const short8*)&sA[cur][(m_off + i * 16 + n16) * BK + quad * 8];
        #pragma unroll
        for (int j = 0; j < NF; ++j)
            bfr[j] = *(const short8*)&sB[cur][(n_off + j * 16 + n16) * BK + quad * 8];
        #pragma unroll
        for (int i = 0; i < NI; ++i) {
            #pragma unroll
            for (int j = 0; j < NF; ++j)
                acc[i][j] = __builtin_amdgcn_mfma_f32_16x16x32_bf16(
                    af[i], bfr[j], acc[i][j], 0, 0, 0);
        }
    }

    // C/D layout: col = lane&15, row = quad*4 + reg
    if (!final_out && n0g >= 2048) {
        // V third -> VT[bh][d][s], packed 4 consecutive s (=rows) per store
        #pragma unroll
        for (int i = 0; i < NI; ++i) {
            #pragma unroll
            for (int j = 0; j < NF; ++j) {
                int row = m0 + m_off + i * 16 + quad * 4;    // r=0 row
                int b_ = row >> 11, s = row & 2047;          // batch, seq
                int cv = (n0g - 2048) + n_off + j * 16 + n16;
                int h_ = cv >> 6, dl = cv & 63;
                u16 pack[4];
                #pragma unroll
                for (int r = 0; r < 4; ++r) pack[r] = f2bf(acc[i][j][r]);
                u16* dst = VT + (((size_t)(b_ * 16 + h_) * 64 + dl) * S_LEN + s);
                *(uint2*)dst = *(uint2*)pack;                // s%4==0 -> 8B aligned
            }
        }
        return;
    }
    const int outmode = final_out ? mode : 0;
    const float oscale = (!final_out && n0g < 1024) ? QSCALE : 1.0f;
    #pragma unroll
    for (int i = 0; i < NI; ++i) {
        #pragma unroll
        for (int j = 0; j < NF; ++j) {
            #pragma unroll
            for (int r = 0; r < 4; ++r) {
                int row = m0 + m_off + i * 16 + quad * 4 + r;
                int col = n0g + n_off + j * 16 + n16;
                size_t idx = (size_t)row * N + col;
                float v = acc[i][j][r] * oscale;
                if (outmode) ((float*)C)[idx] = v;
                else         ((u16*)C)[idx]   = f2bf(v);
            }
        }
    }
}

// ---------------------------------------------------------------------------
// R11 (kept): specialized output projection, 128x64 tile, BK=64.
// Halves barrier-periods (32->16), 16 MFMA/period, LDS 48KB, 2 blocks/CU.
// ---------------------------------------------------------------------------
__global__ __launch_bounds__(256) void gemm_out(
        const u16* __restrict__ A,      // ob (bf16)
        const u16* __restrict__ Braw,   // Wo raw (bf16 view)
        const u16* __restrict__ Bnorm,  // Wo normalized
        void* __restrict__ C,
        const int* __restrict__ flag) {
    __shared__ __align__(16) u16 sA[2][128 * 64];   // 32 KB
    __shared__ __align__(16) u16 sB[2][64 * 64];    // 16 KB

    const int mode = flag[0];
    const u16* B = mode ? Bnorm : Braw;
    const int tid  = threadIdx.x;
    const int lane = tid & 63, wave = tid >> 6;
    const int n16 = lane & 15, quad = lane >> 4;
    const int m0 = blockIdx.x * 128;
    const int n0 = blockIdx.y * 64;
    const int K = DM;

    const int srow = tid >> 3;          // 0..31 (row within 32-row group)
    const int scol = (tid & 7) * 8;     // u16 col within 64-col (128B) row
    const u16* gA = A + (size_t)(m0 + srow) * K + scol;
    const u16* gB = B + (size_t)(n0 + srow) * K + scol;
    const int lofs = wave * 512;        // u16: wave covers 8 rows x 64 cols

    auto issue = [&](int k0, int buf) {
        #pragma unroll
        for (int ia = 0; ia < 4; ++ia)  // A: 4 x 32 rows
            load_lds16(gA + k0 + (size_t)ia * 32 * K, sA[buf] + ia * 2048 + lofs);
        #pragma unroll
        for (int ib = 0; ib < 2; ++ib)  // B: 2 x 32 rows
            load_lds16(gB + k0 + (size_t)ib * 32 * K, sB[buf] + ib * 2048 + lofs);
    };

    const int m_off = (wave >> 1) * 64, n_off = (wave & 1) * 32;
    floatx4 acc[4][2] = {};

    issue(0, 0);
    for (int it = 0; it < 16; ++it) {
        const int cur = it & 1;
        __syncthreads();   // vmcnt(0): buf[cur] staged; fences prev compute
        if (it + 1 < 16) issue((it + 1) * 64, 1 - cur);
        short8 a0[4], a1[4], b0[2], b1[2];
        #pragma unroll
        for (int i = 0; i < 4; ++i) {
            const int rb = (m_off + i * 16 + n16) * 64;
            a0[i] = *(const short8*)&sA[cur][rb + quad * 8];        // k-half 0
            a1[i] = *(const short8*)&sA[cur][rb + 32 + quad * 8];   // k-half 1
        }
        #pragma unroll
        for (int j = 0; j < 2; ++j) {
            const int rb = (n_off + j * 16 + n16) * 64;
            b0[j] = *(const short8*)&sB[cur][rb + quad * 8];
            b1[j] = *(const short8*)&sB[cur][rb + 32 + quad * 8];
        }
        #pragma unroll
        for (int i = 0; i < 4; ++i) {
            #pragma unroll
            for (int j = 0; j < 2; ++j)
                acc[i][j] = __builtin_amdgcn_mfma_f32_16x16x32_bf16(
                    a0[i], b0[j], acc[i][j], 0, 0, 0);
        }
        #pragma unroll
        for (int i = 0; i < 4; ++i) {
            #pragma unroll
            for (int j = 0; j < 2; ++j)
                acc[i][j] = __builtin_amdgcn_mfma_f32_16x16x32_bf16(
                    a1[i], b1[j], acc[i][j], 0, 0, 0);
        }
    }

    // epilogue: C/D layout col=n16, row=quad*4+r; output dtype follows mode
    #pragma unroll
    for (int i = 0; i < 4; ++i) {
        #pragma unroll
        for (int j = 0; j < 2; ++j) {
            #pragma unroll
            for (int r = 0; r < 4; ++r) {
                int row = m0 + m_off + i * 16 + quad * 4 + r;
                int col = n0 + n_off + j * 16 + n16;
                size_t idx = (size_t)row * DM + col;
                float v = acc[i][j][r];
                if (mode) ((float*)C)[idx] = v;
                else      ((u16*)C)[idx]   = f2bf(v);
            }
        }
    }
}

// ---------------------------------------------------------------------------
// Chunked flash attention v7: KVBLK 32 -> 64. R11 budget analysis puts attn
// at ~35-40us, dominated by per-chunk overhead (barrier + P LDS round-trip +
// staging issue), not MFMA. KVBLK=64 halves all per-chunk costs: 5 chunks
// (was 10), 5 barriers, 5 P-round-trips (was 9), staging issues halved;
// MFMA/chunk 8 -> 16 (QK 8 + PV 8, two K-slabs). Window math: every wave
// needs kv [sqb-255, sqb+15] subset of [q0-256, q0+64) = exactly chunks 0-4;
// the old cfirst skip logic disappears. LDS 29.5 -> 45 KB (sK/sVt [64][72]
// 16B-aligned rows, same bank profile as v6; sP single-buffer -- safe: the
// top-of-loop __syncthreads fences iter-c P-reads before iter-c+1 P-writes).
// Occupancy ~4 -> 3 blocks/CU; halved barrier count should dominate.
// Kept: T14 2-deep load pipeline, exp2-fold (Q pre-scaled 0.125*log2e),
// T5 setprio, no-max softmax, deferred row-sum, masked -3e38 -> exp2=0.
// ---------------------------------------------------------------------------
#define NCHUNK 5

__global__ __launch_bounds__(256) void attn_mfma(
        const u16* __restrict__ QKV, const u16* __restrict__ VT,
        u16* __restrict__ O) {
    __shared__ __align__(16) u16 sK[2][64][72];      // 18 KB
    __shared__ __align__(16) u16 sVt[2][64][72];     // 18 KB
    __shared__ __align__(16) u16 sP[4][16][72];      // 9 KB

    const int bh = blockIdx.x;
    const int b  = bh >> 4, h = bh & 15;
    const int q0 = blockIdx.y * 64;
    const int ks0 = q0 - 256;                        // chunk base (64-aligned)
    const int tid = threadIdx.x;
    const u16* base = QKV + (size_t)b * S_LEN * 3072;
    const u16* Kb = base + 1024 + h * 64;
    const u16* Vb = VT + (size_t)bh * 64 * S_LEN;

    const int kRow = tid >> 3;        // K staging: key rows kRow, kRow+32
    const int kSeg = tid & 7;         // 8-elem d segment
    const int vD   = tid >> 2;        // V^T staging: d row 0..63
    const int vSeg = tid & 3;         // kv segments vSeg*8, 32+vSeg*8

    // T14 split: issue_loads (global->reg) / write_lds (reg->LDS)
    auto issue_loads = [&](int c, uint4& k0v, uint4& k1v, uint4& v0v, uint4& v1v) {
        const int ks = ks0 + c * 64;
        int kg0 = ks + kRow, kg1 = kg0 + 32;
        uint4 t0 = {0u,0u,0u,0u}, t1 = {0u,0u,0u,0u};
        if (kg0 >= 0 && kg0 < S_LEN)
            t0 = *(const uint4*)(Kb + (size_t)kg0 * 3072 + kSeg * 8);
        if (kg1 >= 0 && kg1 < S_LEN)
            t1 = *(const uint4*)(Kb + (size_t)kg1 * 3072 + kSeg * 8);
        k0v = t0; k1v = t1;
        int vk0 = ks + vSeg * 8, vk1 = vk0 + 32;
        uint4 u0 = {0u,0u,0u,0u}, u1 = {0u,0u,0u,0u};
        if (vk0 >= 0 && vk0 + 8 <= S_LEN)
            u0 = *(const uint4*)(Vb + (size_t)vD * S_LEN + vk0);
        if (vk1 >= 0 && vk1 + 8 <= S_LEN)
            u1 = *(const uint4*)(Vb + (size_t)vD * S_LEN + vk1);
        v0v = u0; v1v = u1;
    };
    auto write_lds = [&](int buf, const uint4& k0v, const uint4& k1v,
                         const uint4& v0v, const uint4& v1v) {
        *(uint4*)&sK[buf][kRow][kSeg * 8]      = k0v;
        *(uint4*)&sK[buf][kRow + 32][kSeg * 8] = k1v;
        *(uint4*)&sVt[buf][vD][vSeg * 8]       = v0v;
        *(uint4*)&sVt[buf][vD][32 + vSeg * 8]  = v1v;
    };

    const int wave = tid >> 6, lane = tid & 63;
    const int n16 = lane & 15, quad = lane >> 4;
    const int sqb = q0 + wave * 16;
    const int sq_r0 = sqb + quad * 4;

    // Q A-fragments (pre-scaled by 0.125*log2e in GEMM epilogue)
    const u16* qrow = base + (size_t)(sqb + n16) * 3072 + h * 64;
    short8 aq0 = *(const short8*)(qrow + quad * 8);
    short8 aq1 = *(const short8*)(qrow + 32 + quad * 8);

    floatx4 o0 = {0.f,0.f,0.f,0.f}, o1 = o0, o2 = o0, o3 = o0;
    float lsum[4] = {0.f, 0.f, 0.f, 0.f};       // per-lane partial row sums

    uint4 kA0, kA1, vA0, vA1, kB0, kB1, vB0, vB1;
    issue_loads(0, kA0, kA1, vA0, vA1);         // chunk 0 -> regs A
    issue_loads(1, kB0, kB1, vB0, vB1);         // chunk 1 -> regs B
    write_lds(0, kA0, kA1, vA0, vA1);           // chunk 0 -> buf 0

    for (int c = 0; c < NCHUNK; ++c) {
        const int buf = c & 1;
        __syncthreads();                 // buf[c&1] staged; fences sP reuse
        if (c + 2 < NCHUNK) {
            if ((c & 1) == 0) issue_loads(c + 2, kA0, kA1, vA0, vA1);
            else              issue_loads(c + 2, kB0, kB1, vB0, vB1);
        }
        if (c + 1 < NCHUNK) {
            if ((c & 1) == 0) write_lds(1 - buf, kB0, kB1, vB0, vB1);
            else              write_lds(1 - buf, kA0, kA1, vA0, vA1);
        }

        // QK^T: 4 kv-tiles x 2 K-slabs
        floatx4 s0, s1, s2, s3;
        {
            const floatx4 z = {0.f, 0.f, 0.f, 0.f};
            __builtin_amdgcn_s_setprio(1);
            short8 bk;
            bk = *(const short8*)&sK[buf][n16][quad * 8];
            s0 = __builtin_amdgcn_mfma_f32_16x16x32_bf16(aq0, bk, z, 0, 0, 0);
            bk = *(const short8*)&sK[buf][n16][32 + quad * 8];
            s0 = __builtin_amdgcn_mfma_f32_16x16x32_bf16(aq1, bk, s0, 0, 0, 0);
            bk = *(const short8*)&sK[buf][16 + n16][quad * 8];
            s1 = __builtin_amdgcn_mfma_f32_16x16x32_bf16(aq0, bk, z, 0, 0, 0);
            bk = *(const short8*)&sK[buf][16 + n16][32 + quad * 8];
            s1 = __builtin_amdgcn_mfma_f32_16x16x32_bf16(aq1, bk, s1, 0, 0, 0);
            bk = *(const short8*)&sK[buf][32 + n16][quad * 8];
            s2 = __builtin_amdgcn_mfma_f32_16x16x32_bf16(aq0, bk, z, 0, 0, 0);
            bk = *(const short8*)&sK[buf][32 + n16][32 + quad * 8];
            s2 = __builtin_amdgcn_mfma_f32_16x16x32_bf16(aq1, bk, s2, 0, 0, 0);
            bk = *(const short8*)&sK[buf][48 + n16][quad * 8];
            s3 = __builtin_amdgcn_mfma_f32_16x16x32_bf16(aq0, bk, z, 0, 0, 0);
            bk = *(const short8*)&sK[buf][48 + n16][32 + quad * 8];
            s3 = __builtin_amdgcn_mfma_f32_16x16x32_bf16(aq1, bk, s3, 0, 0, 0);
            __builtin_amdgcn_s_setprio(0);
        }

        // mask + exp2 + P write (16 values/lane)
        u16* pw = &sP[wave][0][0];
        const int kgb = ks0 + c * 64 + n16;
        #pragma unroll
        for (int r = 0; r < 4; ++r) {
            int sq = sq_r0 + r;
            int lo = sq - (WIN - 1); if (lo < 0) lo = 0;
            float p;
            p = exp2f((kgb      >= lo && kgb      <= sq) ? s0[r] : -3e38f);
            lsum[r] += p; pw[(quad * 4 + r) * 72 + n16]      = f2bf(p);
            p = exp2f((kgb + 16 >= lo && kgb + 16 <= sq) ? s1[r] : -3e38f);
            lsum[r] += p; pw[(quad * 4 + r) * 72 + 16 + n16] = f2bf(p);
            p = exp2f((kgb + 32 >= lo && kgb + 32 <= sq) ? s2[r] : -3e38f);
            lsum[r] += p; pw[(quad * 4 + r) * 72 + 32 + n16] = f2bf(p);
            p = exp2f((kgb + 48 >= lo && kgb + 48 <= sq) ? s3[r] : -3e38f);
            lsum[r] += p; pw[(quad * 4 + r) * 72 + 48 + n16] = f2bf(p);
        }
        asm volatile("s_waitcnt lgkmcnt(0)" ::: "memory");

        // PV: P (16x64) x V^T, 4 d-tiles x 2 kv-slabs
        short8 pa0 = *(const short8*)&pw[n16 * 72 + quad * 8];
        short8 pa1 = *(const short8*)&pw[n16 * 72 + 32 + quad * 8];
        __builtin_amdgcn_s_setprio(1);
        {
            short8 bv;
            bv = *(const short8*)&sVt[buf][n16][quad * 8];
            o0 = __builtin_amdgcn_mfma_f32_16x16x32_bf16(pa0, bv, o0, 0, 0, 0);
            bv = *(const short8*)&sVt[buf][n16][32 + quad * 8];
            o0 = __builtin_amdgcn_mfma_f32_16x16x32_bf16(pa1, bv, o0, 0, 0, 0);
            bv = *(const short8*)&sVt[buf][16 + n16][quad * 8];
            o1 = __builtin_amdgcn_mfma_f32_16x16x32_bf16(pa0, bv, o1, 0, 0, 0);
            bv = *(const short8*)&sVt[buf][16 + n16][32 + quad * 8];
            o1 = __builtin_amdgcn_mfma_f32_16x16x32_bf16(pa1, bv, o1, 0, 0, 0);
            bv = *(const short8*)&sVt[buf][32 + n16][quad * 8];
            o2 = __builtin_amdgcn_mfma_f32_16x16x32_bf16(pa0, bv, o2, 0, 0, 0);
            bv = *(const short8*)&sVt[buf][32 + n16][32 + quad * 8];
            o2 = __builtin_amdgcn_mfma_f32_16x16x32_bf16(pa1, bv, o2, 0, 0, 0);
            bv = *(const short8*)&sVt[buf][48 + n16][quad * 8];
            o3 = __builtin_amdgcn_mfma_f32_16x16x32_bf16(pa0, bv, o3, 0, 0, 0);
            bv = *(const short8*)&sVt[buf][48 + n16][32 + quad * 8];
            o3 = __builtin_amdgcn_mfma_f32_16x16x32_bf16(pa1, bv, o3, 0, 0, 0);
        }
        __builtin_amdgcn_s_setprio(0);
    }

    // single deferred row-sum reduction (over the 16 n16 lanes)
    #pragma unroll
    for (int r = 0; r < 4; ++r) {
        float s = lsum[r];
        s += __shfl_xor(s, 1);
        s += __shfl_xor(s, 2);
        s += __shfl_xor(s, 4);
        s += __shfl_xor(s, 8);
        lsum[r] = s;
    }

    #pragma unroll
    for (int r = 0; r < 4; ++r) {
        float rl = 1.0f / lsum[r];
        size_t ro = ((size_t)(b * S_LEN + sq_r0 + r)) * DM + h * 64 + n16;
        O[ro]      = f2bf(o0[r] * rl);
        O[ro + 16] = f2bf(o1[r] * rl);
        O[ro + 32] = f2bf(o2[r] * rl);
        O[ro + 48] = f2bf(o3[r] * rl);
    }
}

// ---------------------------------------------------------------------------
extern "C" void kernel_launch(void* const* d_in, const int* in_sizes, int n_in,
                              void* d_out, int out_size, void* d_ws, size_t ws_size,
                              hipStream_t stream) {
    char* ws = (char*)d_ws;
    int* flag = (int*)ws;
    u16* xb   = (u16*)(ws + 1024);
    u16* wcat = xb   + (size_t)NX;
    u16* wob  = wcat + (size_t)3 * NW;
    u16* qkv  = wob  + (size_t)NW;
    u16* ob   = qkv  + (size_t)MROWS * 3 * DM;
    u16* vt   = ob   + (size_t)NX;              // 32 x 64 x 2048 = 8 MB

    const u16* xr  = (const u16*)d_in[0];
    const u16* wqr = (const u16*)d_in[1];
    const u16* wkr = (const u16*)d_in[2];
    const u16* wvr = (const u16*)d_in[3];
    const u16* wor = (const u16*)d_in[4];

    normalize_inputs<<<1024, 256, 0, stream>>>(
        d_in[0], d_in[1], d_in[2], d_in[3], d_in[4], xb, wcat, wob, flag);
    // QKV = x * Wcat^T -> qkv (Q scaled by 0.125*log2e, K) + vt (V transposed)
    gemm_lds<128, 128><<<dim3(MROWS / 128, 3072 / 128), 256, 0, stream>>>(
        xr, xb, wqr, wkr, wvr, wcat, qkv, vt, MROWS, 3 * DM, DM, flag, 0);
    // attention -> ob [4096,1024]  (KVBLK=64: 5 chunks, 5 barriers)
    attn_mfma<<<dim3(BATCH * NHEADS, S_LEN / 64), 256, 0, stream>>>(qkv, vt, ob);
    // out = ob * Wo^T -> d_out [4096,1024]  (128x64 tile, BK=64)
    gemm_out<<<dim3(MROWS / 128, DM / 64), 256, 0, stream>>>(
        ob, wor, wob, d_out, flag);
}